// Round 6
// baseline (178.158 us; speedup 1.0000x reference)
//
#include <hip/hip_runtime.h>

// ---------------------------------------------------------------------------
// Fused attention block: qkv GEMM -> RoPE -> causal SDPA (MFMA) -> out GEMM
// B=2 S=2048 D=1024 H=16 DH=64. bf16 MFMA everywhere.
// MFMA fragment mapping (verified r1-r5): A/B-frag outer=lane&15, k=oct*8+e;
// C/D row=oct*4+r, col=lane&15.
// r6: paired 64-row q-tiles (i,31-i) -> uniform 33 tile-computes/block (r4)
//     + in-lane P w/ permuted V (r5) + l-via-ones-MFMA + tile-blocked V
//     (coalesced staging) + setprio around MFMA clusters.
// ---------------------------------------------------------------------------

typedef __bf16 bf16x8 __attribute__((ext_vector_type(8)));
typedef float f32x4 __attribute__((ext_vector_type(4)));

__device__ __forceinline__ unsigned short f2b(float f) {
  unsigned int u = __builtin_bit_cast(unsigned int, f);
  unsigned int lsb = (u >> 16) & 1u;
  u += 0x7fffu + lsb;  // round-to-nearest-even
  return (unsigned short)(u >> 16);
}
__device__ __forceinline__ float b2f(unsigned short h) {
  unsigned int u = ((unsigned int)h) << 16;
  return __builtin_bit_cast(float, u);
}
__device__ __forceinline__ unsigned int pk2(float a, float b) {
  return (unsigned int)f2b(a) | ((unsigned int)f2b(b) << 16);
}
__device__ __forceinline__ unsigned int cvtpk(float lo, float hi) {
  unsigned int r;
  asm("v_cvt_pk_bf16_f32 %0, %1, %2" : "=v"(r) : "v"(lo), "v"(hi));
  return r;
}
__device__ __forceinline__ void unp8(uint4 v, float* f) {
  unsigned int u[4] = {v.x, v.y, v.z, v.w};
#pragma unroll
  for (int i = 0; i < 4; ++i) {
    f[2 * i] = b2f((unsigned short)(u[i] & 0xffff));
    f[2 * i + 1] = b2f((unsigned short)(u[i] >> 16));
  }
}
__device__ __forceinline__ void gload16(const void* g, void* l) {
  __builtin_amdgcn_global_load_lds(
      (const __attribute__((address_space(1))) unsigned int*)g,
      (__attribute__((address_space(3))) unsigned int*)l, 16, 0, 0);
}

// --------------------------- fp32 -> bf16 convert ---------------------------
__global__ __launch_bounds__(256) void convert_bf16(const float* __restrict__ src,
                                                    unsigned short* __restrict__ dst,
                                                    int n) {
  int i = (blockIdx.x * 256 + threadIdx.x) * 4;
  if (i + 3 < n) {
    float4 v = *(const float4*)&src[i];
    ushort4 o;
    o.x = f2b(v.x); o.y = f2b(v.y); o.z = f2b(v.z); o.w = f2b(v.w);
    *(ushort4*)&dst[i] = o;
  }
}

// -------------------- transpose [K][N] f32 -> [N][K] bf16 -------------------
__global__ __launch_bounds__(256) void transpose_f32_bf16(const float* __restrict__ src,
                                                          unsigned short* __restrict__ dst,
                                                          int K, int N) {
  __shared__ float tile[32][33];
  int n0 = blockIdx.x * 32, k0 = blockIdx.y * 32;
  int c = threadIdx.x & 31, r4 = threadIdx.x >> 5;
#pragma unroll
  for (int p = 0; p < 4; ++p) {
    int r = r4 + p * 8;
    tile[r][c] = src[(size_t)(k0 + r) * N + n0 + c];
  }
  __syncthreads();
#pragma unroll
  for (int p = 0; p < 4; ++p) {
    int r = r4 + p * 8;
    dst[(size_t)(n0 + r) * K + k0 + c] = f2b(tile[c][r]);
  }
}

// --------------------------- bf16 MFMA GEMM --------------------------------
// C[M][N] = A[M][K]*B, B given as BT[N][K], both bf16. Staging via
// global_load_lds (16B) into linear LDS with XOR-swizzled global source.
template <int C_BF16>
__global__ __launch_bounds__(256) void gemm_bt(const unsigned short* __restrict__ A,
                                               const unsigned short* __restrict__ BT,
                                               void* __restrict__ Cp,
                                               int M, int N, int K) {
  __shared__ unsigned short AsL[128 * 32];
  __shared__ unsigned short BsL[128 * 32];
  const int tid = threadIdx.x;
  const int m0 = blockIdx.y * 128, n0 = blockIdx.x * 128;
  const int lane = tid & 63, w = tid >> 6;
  const int wm = (w >> 1) * 64, wn = (w & 1) * 64;
  const int fr = lane & 15, oct = lane >> 4;
  const int l = lane;
  const int srow = (l >> 2);
  const int scol = ((l & 3) ^ ((l >> 3) & 3)) * 8;  // swizzled source col

  f32x4 acc[4][4] = {};

  for (int k0 = 0; k0 < K; k0 += 32) {
    __syncthreads();
#pragma unroll
    for (int p = 0; p < 2; ++p) {
      const int c = w * 2 + p;  // wave-uniform chunk id 0..7
      const int row = c * 16 + srow;
      gload16(&A[(size_t)(m0 + row) * K + k0 + scol], &AsL[c * 512 + l * 8]);
      gload16(&BT[(size_t)(n0 + row) * K + k0 + scol], &BsL[c * 512 + l * 8]);
    }
    __syncthreads();
    bf16x8 af[4], bq[4];
#pragma unroll
    for (int i = 0; i < 4; ++i) {
      int r = wm + i * 16 + fr;
      af[i] = __builtin_bit_cast(
          bf16x8, *(const uint4*)&AsL[r * 32 + (oct ^ ((r >> 1) & 3)) * 8]);
    }
#pragma unroll
    for (int j = 0; j < 4; ++j) {
      int r = wn + j * 16 + fr;
      bq[j] = __builtin_bit_cast(
          bf16x8, *(const uint4*)&BsL[r * 32 + (oct ^ ((r >> 1) & 3)) * 8]);
    }
#pragma unroll
    for (int i = 0; i < 4; ++i)
#pragma unroll
      for (int j = 0; j < 4; ++j)
        acc[i][j] = __builtin_amdgcn_mfma_f32_16x16x32_bf16(af[i], bq[j], acc[i][j], 0, 0, 0);
  }

#pragma unroll
  for (int i = 0; i < 4; ++i)
#pragma unroll
    for (int j = 0; j < 4; ++j)
#pragma unroll
      for (int r = 0; r < 4; ++r) {
        size_t idx = (size_t)(m0 + wm + i * 16 + oct * 4 + r) * N + n0 + wn + j * 16 + fr;
        if (C_BF16)
          ((unsigned short*)Cp)[idx] = f2b(acc[i][j][r]);
        else
          ((float*)Cp)[idx] = acc[i][j][r];
      }
}

// ----------------- prep: RoPE + layout (Q,K rows; V tile-blocked+permuted) --
// qkvb [4096][3072] bf16. Writes Qb,Kb [b*16+h][2048][64] bf16 (Q scaled by
// 0.125*log2e), Vtg tile-blocked [b*16+h][kb(32)][d(64)][64] bf16 with
// in-tile k-permutation j = m*32+oct*8+t'*4+r <-> k_phys = m*32+t'*16+oct*4+r
// matching the in-lane P pack order of the attention kernel.
__global__ __launch_bounds__(256) void prep_kernel(const unsigned short* __restrict__ qkvb,
                                                   const float* __restrict__ freqs,
                                                   unsigned short* __restrict__ Qb,
                                                   unsigned short* __restrict__ Kb,
                                                   unsigned short* __restrict__ Vtg) {
  const int sb = blockIdx.x, h = blockIdx.y, b = blockIdx.z;
  const int tid = threadIdx.x;
  __shared__ float Vs[64][65];
  const int sl = tid >> 2, c8 = (tid & 3) * 8;
  const int s = sb * 64 + sl;
  const size_t tok = (size_t)(b * 2048 + s);
  const unsigned short* row = qkvb + tok * 3072 + h * 64;
  const float QSCALE = 0.125f * 1.44269504f;

  float cl[8], snl[8], ch[8], snh[8];
#pragma unroll
  for (int e = 0; e < 8; ++e) {
    float fl = freqs[s * 64 + c8 + e];
    float fh = freqs[s * 64 + 32 + c8 + e];
    cl[e] = cosf(fl); snl[e] = sinf(fl);
    ch[e] = cosf(fh); snh[e] = sinf(fh);
  }
  const size_t obase = ((size_t)(b * 16 + h) * 2048 + s) * 64;

  // Q (scaled)
  {
    float lo[8], hi[8];
    unp8(*(const uint4*)(row + c8), lo);
    unp8(*(const uint4*)(row + 32 + c8), hi);
    float olo[8], ohi[8];
#pragma unroll
    for (int e = 0; e < 8; ++e) {
      olo[e] = (lo[e] * cl[e] - hi[e] * snl[e]) * QSCALE;
      ohi[e] = (hi[e] * ch[e] + lo[e] * snh[e]) * QSCALE;
    }
    uint4 w0, w1;
    w0.x = pk2(olo[0], olo[1]); w0.y = pk2(olo[2], olo[3]);
    w0.z = pk2(olo[4], olo[5]); w0.w = pk2(olo[6], olo[7]);
    w1.x = pk2(ohi[0], ohi[1]); w1.y = pk2(ohi[2], ohi[3]);
    w1.z = pk2(ohi[4], ohi[5]); w1.w = pk2(ohi[6], ohi[7]);
    *(uint4*)(Qb + obase + c8) = w0;
    *(uint4*)(Qb + obase + 32 + c8) = w1;
  }
  // K
  {
    float lo[8], hi[8];
    unp8(*(const uint4*)(row + 1024 + c8), lo);
    unp8(*(const uint4*)(row + 1024 + 32 + c8), hi);
    float olo[8], ohi[8];
#pragma unroll
    for (int e = 0; e < 8; ++e) {
      olo[e] = lo[e] * cl[e] - hi[e] * snl[e];
      ohi[e] = hi[e] * ch[e] + lo[e] * snh[e];
    }
    uint4 w0, w1;
    w0.x = pk2(olo[0], olo[1]); w0.y = pk2(olo[2], olo[3]);
    w0.z = pk2(olo[4], olo[5]); w0.w = pk2(olo[6], olo[7]);
    w1.x = pk2(ohi[0], ohi[1]); w1.y = pk2(ohi[2], ohi[3]);
    w1.z = pk2(ohi[4], ohi[5]); w1.w = pk2(ohi[6], ohi[7]);
    *(uint4*)(Kb + obase + c8) = w0;
    *(uint4*)(Kb + obase + 32 + c8) = w1;
  }
  // V -> LDS f32, then tile-blocked + k-permuted bf16 out
  {
    float lo[8], hi[8];
    unp8(*(const uint4*)(row + 2048 + c8), lo);
    unp8(*(const uint4*)(row + 2048 + 32 + c8), hi);
#pragma unroll
    for (int e = 0; e < 8; ++e) {
      Vs[sl][c8 + e] = lo[e];
      Vs[sl][32 + c8 + e] = hi[e];
    }
  }
  __syncthreads();
  {
    const int d = tid >> 2, q2 = tid & 3;
    const int m = q2 >> 1, tp = q2 & 1;
    const int sc0 = q2 * 16;  // k_phys base for this thread
    const size_t vbase = (((size_t)(b * 16 + h) * 32 + sb) * 64 + d) * 64;
#pragma unroll
    for (int g = 0; g < 4; ++g) {  // g = oct of k_phys
      ushort4 u;
      u.x = f2b(Vs[sc0 + g * 4 + 0][d]);
      u.y = f2b(Vs[sc0 + g * 4 + 1][d]);
      u.z = f2b(Vs[sc0 + g * 4 + 2][d]);
      u.w = f2b(Vs[sc0 + g * 4 + 3][d]);
      *(ushort4*)(Vtg + vbase + m * 32 + g * 8 + tp * 4) = u;
    }
  }
}

// --------------------------- MFMA flash attention ---------------------------
// Block = (pair, h, b): q-tiles {pair, 31-pair} (64 rows each) -> uniform 33
// tile-computes/block. 256 threads = 4 waves; wave w owns rows w*16..+15 of
// each tile. Swapped QK^T (S^T = mfma(K,Q)): lane owns q-column fr. P packs
// in-lane (cvt_pk) against k-permuted V; l via all-ones B-fragment MFMA.
__global__ __launch_bounds__(256) void attn_mfma(const unsigned short* __restrict__ Qb,
                                                 const unsigned short* __restrict__ Kb,
                                                 const unsigned short* __restrict__ Vtg,
                                                 unsigned short* __restrict__ attnb) {
  const int h = blockIdx.y, b = blockIdx.z;
  const int qt0 = blockIdx.x;   // 0..15
  const int qt1 = 31 - qt0;     // 16..31
  const int tid = threadIdx.x, lane = tid & 63, w = tid >> 6;
  const int fr = lane & 15, oct = lane >> 4;

  __shared__ unsigned short Ks[2][64][72];
  __shared__ unsigned short Vt[2][64][72];

  const size_t bh = (size_t)(b * 16 + h);
  const int qtv[2] = {qt0, qt1};

  bf16x8 qf[2][2];
#pragma unroll
  for (int tl = 0; tl < 2; ++tl) {
    const unsigned short* Qp = Qb + (bh * 2048 + qtv[tl] * 64 + w * 16 + fr) * 64;
    qf[tl][0] = __builtin_bit_cast(bf16x8, *(const uint4*)(Qp + oct * 8));
    qf[tl][1] = __builtin_bit_cast(bf16x8, *(const uint4*)(Qp + 32 + oct * 8));
  }

  float m_prev[2] = {-1e30f, -1e30f};
  f32x4 acc[2][4] = {};  // acc[tl][t2][r] = O[q=qt*64+w*16+oct*4+r][d=t2*16+fr]
  f32x4 accl[2] = {};    // l[q=...oct*4+r] via ones-column (replicated over fr)

  uint4 onesu;
  onesu.x = 0x3F803F80u; onesu.y = 0x3F803F80u;
  onesu.z = 0x3F803F80u; onesu.w = 0x3F803F80u;
  const bf16x8 onesf = __builtin_bit_cast(bf16x8, onesu);

  // staging: 256 threads, K tile + V tile (identical addressing, tile-blocked V)
  const int sk = tid >> 2, sc = (tid & 3) * 16;
  const unsigned short* Kp = Kb + bh * 2048 * 64;
  const unsigned short* Vp = Vtg + bh * 32 * 64 * 64;

  uint4 kr0, kr1, vr0, vr1;
  auto load_tile = [&](int kb) {
    const unsigned short* ks = Kp + (size_t)(kb * 64 + sk) * 64 + sc;
    kr0 = *(const uint4*)ks;
    kr1 = *(const uint4*)(ks + 8);
    const unsigned short* vs = Vp + (size_t)(kb * 64 + sk) * 64 + sc;
    vr0 = *(const uint4*)vs;
    vr1 = *(const uint4*)(vs + 8);
  };
  auto store_tile = [&](int buf) {
    *(uint4*)&Ks[buf][sk][sc] = kr0;
    *(uint4*)&Ks[buf][sk][sc + 8] = kr1;
    *(uint4*)&Vt[buf][sk][sc] = vr0;
    *(uint4*)&Vt[buf][sk][sc + 8] = vr1;
  };

  load_tile(0);
  store_tile(0);
  __syncthreads();
  int cur = 0;
  const int nk = qt1 + 1;

  for (int kb = 0; kb < nk; ++kb) {
    if (kb + 1 < nk) load_tile(kb + 1);  // prefetch next tile into registers

    // K and V fragments (shared by both q-tiles)
    bf16x8 kf0[4], kf1[4], vf0[4], vf1[4];
#pragma unroll
    for (int t = 0; t < 4; ++t) {
      kf0[t] = __builtin_bit_cast(bf16x8, *(const uint4*)&Ks[cur][t * 16 + fr][oct * 8]);
      kf1[t] = __builtin_bit_cast(bf16x8, *(const uint4*)&Ks[cur][t * 16 + fr][32 + oct * 8]);
      vf0[t] = __builtin_bit_cast(bf16x8, *(const uint4*)&Vt[cur][t * 16 + fr][oct * 8]);
      vf1[t] = __builtin_bit_cast(bf16x8, *(const uint4*)&Vt[cur][t * 16 + fr][32 + oct * 8]);
    }

#pragma unroll
    for (int tl = 0; tl < 2; ++tl) {
      if (tl == 0 && kb > qt0) continue;

      // S^T (log2-domain): s4[t][r] = S[k=kb*64+t*16+oct*4+r][q=qt*64+w*16+fr]
      f32x4 s4[4];
      __builtin_amdgcn_s_setprio(1);
#pragma unroll
      for (int t = 0; t < 4; ++t) {
        f32x4 s = {};
        s = __builtin_amdgcn_mfma_f32_16x16x32_bf16(kf0[t], qf[tl][0], s, 0, 0, 0);
        s = __builtin_amdgcn_mfma_f32_16x16x32_bf16(kf1[t], qf[tl][1], s, 0, 0, 0);
        s4[t] = s;
      }
      __builtin_amdgcn_s_setprio(0);
      if (kb == qtv[tl]) {  // diagonal: mask k > q
#pragma unroll
        for (int t = 0; t < 4; ++t)
#pragma unroll
          for (int r = 0; r < 4; ++r)
            if (t * 16 + oct * 4 + r > w * 16 + fr) s4[t][r] = -1e30f;
      }

      // online softmax per lane (q-column = fr); defer-max (THR=11 in log2)
      float pm = -1e30f;
#pragma unroll
      for (int t = 0; t < 4; ++t)
#pragma unroll
        for (int r = 0; r < 4; ++r) pm = fmaxf(pm, s4[t][r]);
      pm = fmaxf(pm, __shfl_xor(pm, 16));
      pm = fmaxf(pm, __shfl_xor(pm, 32));
      const bool need = __any(pm - m_prev[tl] > 11.0f);
      if (need) {
        float mnew = fmaxf(m_prev[tl], pm);
        float cf = exp2f(m_prev[tl] - mnew);
        m_prev[tl] = mnew;
        float cfr[4];
#pragma unroll
        for (int r = 0; r < 4; ++r) cfr[r] = __shfl(cf, oct * 4 + r);
#pragma unroll
        for (int t2 = 0; t2 < 4; ++t2)
#pragma unroll
          for (int r = 0; r < 4; ++r) acc[tl][t2][r] *= cfr[r];
#pragma unroll
        for (int r = 0; r < 4; ++r) accl[tl][r] *= cfr[r];
      }
      const float mcur = m_prev[tl];
#pragma unroll
      for (int t = 0; t < 4; ++t)
#pragma unroll
        for (int r = 0; r < 4; ++r) s4[t][r] = exp2f(s4[t][r] - mcur);

      // in-lane P pack
      uint4 p0, p1;
      p0.x = cvtpk(s4[0][0], s4[0][1]); p0.y = cvtpk(s4[0][2], s4[0][3]);
      p0.z = cvtpk(s4[1][0], s4[1][1]); p0.w = cvtpk(s4[1][2], s4[1][3]);
      p1.x = cvtpk(s4[2][0], s4[2][1]); p1.y = cvtpk(s4[2][2], s4[2][3]);
      p1.z = cvtpk(s4[3][0], s4[3][1]); p1.w = cvtpk(s4[3][2], s4[3][3]);
      const bf16x8 pa0 = __builtin_bit_cast(bf16x8, p0);
      const bf16x8 pa1 = __builtin_bit_cast(bf16x8, p1);

      // PV against k-permuted V + l via ones-column
      __builtin_amdgcn_s_setprio(1);
#pragma unroll
      for (int t2 = 0; t2 < 4; ++t2) {
        f32x4 a = acc[tl][t2];
        a = __builtin_amdgcn_mfma_f32_16x16x32_bf16(pa0, vf0[t2], a, 0, 0, 0);
        a = __builtin_amdgcn_mfma_f32_16x16x32_bf16(pa1, vf1[t2], a, 0, 0, 0);
        acc[tl][t2] = a;
      }
      {
        f32x4 a = accl[tl];
        a = __builtin_amdgcn_mfma_f32_16x16x32_bf16(pa0, onesf, a, 0, 0, 0);
        a = __builtin_amdgcn_mfma_f32_16x16x32_bf16(pa1, onesf, a, 0, 0, 0);
        accl[tl] = a;
      }
      __builtin_amdgcn_s_setprio(0);
    }

    if (kb + 1 < nk) store_tile(cur ^ 1);  // waits vmcnt, writes other buffer
    __syncthreads();
    cur ^= 1;
  }

  // epilogue: normalize by l (already in acc layout), write bf16
#pragma unroll
  for (int tl = 0; tl < 2; ++tl) {
#pragma unroll
    for (int r = 0; r < 4; ++r) {
      float linv = 1.f / accl[tl][r];
      size_t orow = (size_t)(b * 2048 + qtv[tl] * 64 + w * 16 + oct * 4 + r);
#pragma unroll
      for (int t2 = 0; t2 < 4; ++t2)
        attnb[orow * 1024 + h * 64 + t2 * 16 + fr] = f2b(acc[tl][t2][r] * linv);
    }
  }
}

// ---------------------------------------------------------------------------
extern "C" void kernel_launch(void* const* d_in, const int* in_sizes, int n_in,
                              void* d_out, int out_size, void* d_ws, size_t ws_size,
                              hipStream_t stream) {
  const float* x     = (const float*)d_in[0];  // [2,2048,1024]
  const float* w_qkv = (const float*)d_in[1];  // [1024,3072]
  const float* w_out = (const float*)d_in[2];  // [1024,1024]
  const float* freqs = (const float*)d_in[3];  // [2048,64]
  float* out = (float*)d_out;

  char* ws = (char*)d_ws;
  unsigned short* qkvb = (unsigned short*)(ws);             // 25165824
  unsigned short* Qb   = (unsigned short*)(ws + 25165824);  // 8388608
  unsigned short* Kb   = (unsigned short*)(ws + 33554432);  // 8388608
  unsigned short* Vtg  = (unsigned short*)(ws + 41943040);  // 8388608
  unsigned short* attnb= (unsigned short*)(ws + 50331648);  // 8388608
  unsigned short* wqT  = (unsigned short*)(ws + 58720256);  // 6291456
  unsigned short* woT  = (unsigned short*)(ws + 65011712);  // 2097152
  unsigned short* xb   = (unsigned short*)(ws + 67108864);  // 8388608
  // total ws use: 75497472 bytes (72 MiB)

  convert_bf16<<<4096, 256, 0, stream>>>(x, xb, 4096 * 1024);
  transpose_f32_bf16<<<dim3(96, 32), 256, 0, stream>>>(w_qkv, wqT, 1024, 3072);
  transpose_f32_bf16<<<dim3(32, 32), 256, 0, stream>>>(w_out, woT, 1024, 1024);
  gemm_bt<1><<<dim3(24, 32), 256, 0, stream>>>(xb, wqT, qkvb, 4096, 3072, 1024);
  prep_kernel<<<dim3(32, 16, 2), 256, 0, stream>>>(qkvb, freqs, Qb, Kb, Vtg);
  attn_mfma<<<dim3(16, 16, 2), 256, 0, stream>>>(Qb, Kb, Vtg, attnb);
  gemm_bt<0><<<dim3(8, 32), 256, 0, stream>>>(attnb, woT, out, 4096, 1024, 1024);
}

// Round 7
// 139.101 us; speedup vs baseline: 1.2808x; 1.2808x over previous
//
#include <hip/hip_runtime.h>

// ---------------------------------------------------------------------------
// Fused attention block: qkv GEMM -> RoPE -> causal SDPA (MFMA) -> out GEMM
// B=2 S=2048 D=1024 H=16 DH=64. bf16 MFMA everywhere.
// MFMA fragment mapping (verified r1-r6): A/B-frag outer=lane&15, k=oct*8+e;
// C/D row=oct*4+r, col=lane&15.
// r7: native v_exp_f32 (__builtin_amdgcn_exp2f) -- exp2f was compiling to the
//     slow OCML sequence (~400 VALU-cyc/unit); shfl-free common-path softmax
//     (defer-max + __any, l via ones-MFMA); transient K/V frags (VGPR down);
//     complementary-nk block swizzle (uniform per-CU work).
// ---------------------------------------------------------------------------

typedef __bf16 bf16x8 __attribute__((ext_vector_type(8)));
typedef float f32x4 __attribute__((ext_vector_type(4)));

__device__ __forceinline__ unsigned short f2b(float f) {
  unsigned int u = __builtin_bit_cast(unsigned int, f);
  unsigned int lsb = (u >> 16) & 1u;
  u += 0x7fffu + lsb;  // round-to-nearest-even
  return (unsigned short)(u >> 16);
}
__device__ __forceinline__ float b2f(unsigned short h) {
  unsigned int u = ((unsigned int)h) << 16;
  return __builtin_bit_cast(float, u);
}
__device__ __forceinline__ unsigned int pk2(float a, float b) {
  return (unsigned int)f2b(a) | ((unsigned int)f2b(b) << 16);
}
__device__ __forceinline__ unsigned int cvtpk(float lo, float hi) {
  unsigned int r;
  asm("v_cvt_pk_bf16_f32 %0, %1, %2" : "=v"(r) : "v"(lo), "v"(hi));
  return r;
}
__device__ __forceinline__ void unp8(uint4 v, float* f) {
  unsigned int u[4] = {v.x, v.y, v.z, v.w};
#pragma unroll
  for (int i = 0; i < 4; ++i) {
    f[2 * i] = b2f((unsigned short)(u[i] & 0xffff));
    f[2 * i + 1] = b2f((unsigned short)(u[i] >> 16));
  }
}
__device__ __forceinline__ void gload16(const void* g, void* l) {
  __builtin_amdgcn_global_load_lds(
      (const __attribute__((address_space(1))) unsigned int*)g,
      (__attribute__((address_space(3))) unsigned int*)l, 16, 0, 0);
}

// --------------------------- fp32 -> bf16 convert ---------------------------
__global__ __launch_bounds__(256) void convert_bf16(const float* __restrict__ src,
                                                    unsigned short* __restrict__ dst,
                                                    int n) {
  int i = (blockIdx.x * 256 + threadIdx.x) * 4;
  if (i + 3 < n) {
    float4 v = *(const float4*)&src[i];
    ushort4 o;
    o.x = f2b(v.x); o.y = f2b(v.y); o.z = f2b(v.z); o.w = f2b(v.w);
    *(ushort4*)&dst[i] = o;
  }
}

// -------------------- transpose [K][N] f32 -> [N][K] bf16 -------------------
__global__ __launch_bounds__(256) void transpose_f32_bf16(const float* __restrict__ src,
                                                          unsigned short* __restrict__ dst,
                                                          int K, int N) {
  __shared__ float tile[32][33];
  int n0 = blockIdx.x * 32, k0 = blockIdx.y * 32;
  int c = threadIdx.x & 31, r4 = threadIdx.x >> 5;
#pragma unroll
  for (int p = 0; p < 4; ++p) {
    int r = r4 + p * 8;
    tile[r][c] = src[(size_t)(k0 + r) * N + n0 + c];
  }
  __syncthreads();
#pragma unroll
  for (int p = 0; p < 4; ++p) {
    int r = r4 + p * 8;
    dst[(size_t)(n0 + r) * K + k0 + c] = f2b(tile[c][r]);
  }
}

// --------------------------- bf16 MFMA GEMM --------------------------------
// C[M][N] = A[M][K]*B, B given as BT[N][K], both bf16. Staging via
// global_load_lds (16B) into linear LDS with XOR-swizzled global source.
template <int C_BF16>
__global__ __launch_bounds__(256) void gemm_bt(const unsigned short* __restrict__ A,
                                               const unsigned short* __restrict__ BT,
                                               void* __restrict__ Cp,
                                               int M, int N, int K) {
  __shared__ unsigned short AsL[128 * 32];
  __shared__ unsigned short BsL[128 * 32];
  const int tid = threadIdx.x;
  const int m0 = blockIdx.y * 128, n0 = blockIdx.x * 128;
  const int lane = tid & 63, w = tid >> 6;
  const int wm = (w >> 1) * 64, wn = (w & 1) * 64;
  const int fr = lane & 15, oct = lane >> 4;
  const int l = lane;
  const int srow = (l >> 2);
  const int scol = ((l & 3) ^ ((l >> 3) & 3)) * 8;  // swizzled source col

  f32x4 acc[4][4] = {};

  for (int k0 = 0; k0 < K; k0 += 32) {
    __syncthreads();
#pragma unroll
    for (int p = 0; p < 2; ++p) {
      const int c = w * 2 + p;  // wave-uniform chunk id 0..7
      const int row = c * 16 + srow;
      gload16(&A[(size_t)(m0 + row) * K + k0 + scol], &AsL[c * 512 + l * 8]);
      gload16(&BT[(size_t)(n0 + row) * K + k0 + scol], &BsL[c * 512 + l * 8]);
    }
    __syncthreads();
    bf16x8 af[4], bq[4];
#pragma unroll
    for (int i = 0; i < 4; ++i) {
      int r = wm + i * 16 + fr;
      af[i] = __builtin_bit_cast(
          bf16x8, *(const uint4*)&AsL[r * 32 + (oct ^ ((r >> 1) & 3)) * 8]);
    }
#pragma unroll
    for (int j = 0; j < 4; ++j) {
      int r = wn + j * 16 + fr;
      bq[j] = __builtin_bit_cast(
          bf16x8, *(const uint4*)&BsL[r * 32 + (oct ^ ((r >> 1) & 3)) * 8]);
    }
#pragma unroll
    for (int i = 0; i < 4; ++i)
#pragma unroll
      for (int j = 0; j < 4; ++j)
        acc[i][j] = __builtin_amdgcn_mfma_f32_16x16x32_bf16(af[i], bq[j], acc[i][j], 0, 0, 0);
  }

#pragma unroll
  for (int i = 0; i < 4; ++i)
#pragma unroll
    for (int j = 0; j < 4; ++j)
#pragma unroll
      for (int r = 0; r < 4; ++r) {
        size_t idx = (size_t)(m0 + wm + i * 16 + oct * 4 + r) * N + n0 + wn + j * 16 + fr;
        if (C_BF16)
          ((unsigned short*)Cp)[idx] = f2b(acc[i][j][r]);
        else
          ((float*)Cp)[idx] = acc[i][j][r];
      }
}

// ----------------- prep: RoPE + layout (Q,K rows; V tile-blocked+permuted) --
// qkvb [4096][3072] bf16. Writes Qb,Kb [b*16+h][2048][64] bf16 (Q scaled by
// 0.125*log2e), Vtg tile-blocked [b*16+h][kb(32)][d(64)][64] bf16 with
// in-tile k-permutation j = m*32+oct*8+t'*4+r <-> k_phys = m*32+t'*16+oct*4+r
// matching the in-lane P pack order of the attention kernel.
__global__ __launch_bounds__(256) void prep_kernel(const unsigned short* __restrict__ qkvb,
                                                   const float* __restrict__ freqs,
                                                   unsigned short* __restrict__ Qb,
                                                   unsigned short* __restrict__ Kb,
                                                   unsigned short* __restrict__ Vtg) {
  const int sb = blockIdx.x, h = blockIdx.y, b = blockIdx.z;
  const int tid = threadIdx.x;
  __shared__ float Vs[64][65];
  const int sl = tid >> 2, c8 = (tid & 3) * 8;
  const int s = sb * 64 + sl;
  const size_t tok = (size_t)(b * 2048 + s);
  const unsigned short* row = qkvb + tok * 3072 + h * 64;
  const float QSCALE = 0.125f * 1.44269504f;

  float cl[8], snl[8], ch[8], snh[8];
#pragma unroll
  for (int e = 0; e < 8; ++e) {
    float fl = freqs[s * 64 + c8 + e];
    float fh = freqs[s * 64 + 32 + c8 + e];
    cl[e] = cosf(fl); snl[e] = sinf(fl);
    ch[e] = cosf(fh); snh[e] = sinf(fh);
  }
  const size_t obase = ((size_t)(b * 16 + h) * 2048 + s) * 64;

  // Q (scaled)
  {
    float lo[8], hi[8];
    unp8(*(const uint4*)(row + c8), lo);
    unp8(*(const uint4*)(row + 32 + c8), hi);
    float olo[8], ohi[8];
#pragma unroll
    for (int e = 0; e < 8; ++e) {
      olo[e] = (lo[e] * cl[e] - hi[e] * snl[e]) * QSCALE;
      ohi[e] = (hi[e] * ch[e] + lo[e] * snh[e]) * QSCALE;
    }
    uint4 w0, w1;
    w0.x = pk2(olo[0], olo[1]); w0.y = pk2(olo[2], olo[3]);
    w0.z = pk2(olo[4], olo[5]); w0.w = pk2(olo[6], olo[7]);
    w1.x = pk2(ohi[0], ohi[1]); w1.y = pk2(ohi[2], ohi[3]);
    w1.z = pk2(ohi[4], ohi[5]); w1.w = pk2(ohi[6], ohi[7]);
    *(uint4*)(Qb + obase + c8) = w0;
    *(uint4*)(Qb + obase + 32 + c8) = w1;
  }
  // K
  {
    float lo[8], hi[8];
    unp8(*(const uint4*)(row + 1024 + c8), lo);
    unp8(*(const uint4*)(row + 1024 + 32 + c8), hi);
    float olo[8], ohi[8];
#pragma unroll
    for (int e = 0; e < 8; ++e) {
      olo[e] = lo[e] * cl[e] - hi[e] * snl[e];
      ohi[e] = hi[e] * ch[e] + lo[e] * snh[e];
    }
    uint4 w0, w1;
    w0.x = pk2(olo[0], olo[1]); w0.y = pk2(olo[2], olo[3]);
    w0.z = pk2(olo[4], olo[5]); w0.w = pk2(olo[6], olo[7]);
    w1.x = pk2(ohi[0], ohi[1]); w1.y = pk2(ohi[2], ohi[3]);
    w1.z = pk2(ohi[4], ohi[5]); w1.w = pk2(ohi[6], ohi[7]);
    *(uint4*)(Kb + obase + c8) = w0;
    *(uint4*)(Kb + obase + 32 + c8) = w1;
  }
  // V -> LDS f32, then tile-blocked + k-permuted bf16 out
  {
    float lo[8], hi[8];
    unp8(*(const uint4*)(row + 2048 + c8), lo);
    unp8(*(const uint4*)(row + 2048 + 32 + c8), hi);
#pragma unroll
    for (int e = 0; e < 8; ++e) {
      Vs[sl][c8 + e] = lo[e];
      Vs[sl][32 + c8 + e] = hi[e];
    }
  }
  __syncthreads();
  {
    const int d = tid >> 2, q2 = tid & 3;
    const int m = q2 >> 1, tp = q2 & 1;
    const int sc0 = q2 * 16;  // k_phys base for this thread
    const size_t vbase = (((size_t)(b * 16 + h) * 32 + sb) * 64 + d) * 64;
#pragma unroll
    for (int g = 0; g < 4; ++g) {  // g = oct of k_phys
      ushort4 u;
      u.x = f2b(Vs[sc0 + g * 4 + 0][d]);
      u.y = f2b(Vs[sc0 + g * 4 + 1][d]);
      u.z = f2b(Vs[sc0 + g * 4 + 2][d]);
      u.w = f2b(Vs[sc0 + g * 4 + 3][d]);
      *(ushort4*)(Vtg + vbase + m * 32 + g * 8 + tp * 4) = u;
    }
  }
}

// --------------------------- MFMA flash attention ---------------------------
// Block = (pair, h, b): q-tiles {p, 31-p} (64 rows each) -> uniform 33
// tile-computes/block; complementary-nk swizzle across b so each CU's two
// co-resident blocks sum to nk=49. 256 threads = 4 waves; wave w owns rows
// w*16..+15 of each tile. Swapped QK^T (S^T = mfma(K,Q)): lane owns q-column
// fr. Defer-max softmax with shfl-free common path (__any threshold check);
// l via ones-column MFMA; in-lane P pack (cvt_pk) against k-permuted V.
__global__ __launch_bounds__(256) void attn_mfma(const unsigned short* __restrict__ Qb,
                                                 const unsigned short* __restrict__ Kb,
                                                 const unsigned short* __restrict__ Vtg,
                                                 unsigned short* __restrict__ attnb) {
  const int h = blockIdx.y, b = blockIdx.z;
  const int p0 = (blockIdx.x + h) & 15;
  const int qt0 = b == 0 ? p0 : 15 - p0;  // complementary nk across b
  const int qt1 = 31 - qt0;
  const int tid = threadIdx.x, lane = tid & 63, w = tid >> 6;
  const int fr = lane & 15, oct = lane >> 4;

  __shared__ unsigned short Ks[2][64][72];
  __shared__ unsigned short Vt[2][64][72];

  const size_t bh = (size_t)(b * 16 + h);
  const int qtv[2] = {qt0, qt1};

  bf16x8 qf[2][2];
#pragma unroll
  for (int tl = 0; tl < 2; ++tl) {
    const unsigned short* Qp = Qb + (bh * 2048 + qtv[tl] * 64 + w * 16 + fr) * 64;
    qf[tl][0] = __builtin_bit_cast(bf16x8, *(const uint4*)(Qp + oct * 8));
    qf[tl][1] = __builtin_bit_cast(bf16x8, *(const uint4*)(Qp + 32 + oct * 8));
  }

  float m_prev[2] = {-1e30f, -1e30f};
  f32x4 acc[2][4] = {};  // acc[tl][t2][r] = O[q=qt*64+w*16+oct*4+r][d=t2*16+fr]
  f32x4 accl[2] = {};    // l in acc layout via ones-column MFMA

  uint4 onesu;
  onesu.x = 0x3F803F80u; onesu.y = 0x3F803F80u;
  onesu.z = 0x3F803F80u; onesu.w = 0x3F803F80u;
  const bf16x8 onesf = __builtin_bit_cast(bf16x8, onesu);

  // staging pointers (advance 64*64 elements per k-tile)
  const int sk = tid >> 2, sc = (tid & 3) * 16;
  const unsigned short* kp = Kb + bh * 2048 * 64 + (size_t)sk * 64 + sc;
  const unsigned short* vp = Vtg + bh * 32 * 64 * 64 + (size_t)sk * 64 + sc;

  uint4 kr0, kr1, vr0, vr1;
  kr0 = *(const uint4*)kp; kr1 = *(const uint4*)(kp + 8);
  vr0 = *(const uint4*)vp; vr1 = *(const uint4*)(vp + 8);
  *(uint4*)&Ks[0][sk][sc] = kr0;
  *(uint4*)&Ks[0][sk][sc + 8] = kr1;
  *(uint4*)&Vt[0][sk][sc] = vr0;
  *(uint4*)&Vt[0][sk][sc + 8] = vr1;
  __syncthreads();
  int cur = 0;
  const int nk = qt1 + 1;

  for (int kb = 0; kb < nk; ++kb) {
    if (kb + 1 < nk) {  // prefetch next tile into registers
      kp += 4096; vp += 4096;
      kr0 = *(const uint4*)kp; kr1 = *(const uint4*)(kp + 8);
      vr0 = *(const uint4*)vp; vr1 = *(const uint4*)(vp + 8);
    }

#pragma unroll
    for (int tl = 0; tl < 2; ++tl) {
      if (tl == 0 && kb > qt0) continue;

      // S^T (log2-domain): s4[t][r] = S[k=kb*64+t*16+oct*4+r][q=qt*64+w*16+fr]
      f32x4 s4[4];
      __builtin_amdgcn_s_setprio(1);
#pragma unroll
      for (int t = 0; t < 4; ++t) {
        bf16x8 kf0 = __builtin_bit_cast(bf16x8, *(const uint4*)&Ks[cur][t * 16 + fr][oct * 8]);
        bf16x8 kf1 = __builtin_bit_cast(bf16x8, *(const uint4*)&Ks[cur][t * 16 + fr][32 + oct * 8]);
        f32x4 s = {};
        s = __builtin_amdgcn_mfma_f32_16x16x32_bf16(kf0, qf[tl][0], s, 0, 0, 0);
        s = __builtin_amdgcn_mfma_f32_16x16x32_bf16(kf1, qf[tl][1], s, 0, 0, 0);
        s4[t] = s;
      }
      __builtin_amdgcn_s_setprio(0);
      if (kb == qtv[tl]) {  // diagonal: mask k > q
#pragma unroll
        for (int t = 0; t < 4; ++t)
#pragma unroll
          for (int r = 0; r < 4; ++r)
            if (t * 16 + oct * 4 + r > w * 16 + fr) s4[t][r] = -1e30f;
      }

      // defer-max softmax; shfl-free common path
      float pm = -1e30f;
#pragma unroll
      for (int t = 0; t < 4; ++t)
#pragma unroll
        for (int r = 0; r < 4; ++r) pm = fmaxf(pm, s4[t][r]);
      const bool need = __any(pm - m_prev[tl] > 11.0f);
      if (need) {  // rare: full reduce + rescale (wave-uniform branch)
        float pmf = fmaxf(pm, __shfl_xor(pm, 16));
        pmf = fmaxf(pmf, __shfl_xor(pmf, 32));
        float mnew = fmaxf(m_prev[tl], pmf);
        float cf = __builtin_amdgcn_exp2f(m_prev[tl] - mnew);
        m_prev[tl] = mnew;
        float cfr[4];
#pragma unroll
        for (int r = 0; r < 4; ++r) cfr[r] = __shfl(cf, oct * 4 + r);
#pragma unroll
        for (int t2 = 0; t2 < 4; ++t2)
#pragma unroll
          for (int r = 0; r < 4; ++r) acc[tl][t2][r] *= cfr[r];
#pragma unroll
        for (int r = 0; r < 4; ++r) accl[tl][r] *= cfr[r];
      }
      const float mc = m_prev[tl];
#pragma unroll
      for (int t = 0; t < 4; ++t)
#pragma unroll
        for (int r = 0; r < 4; ++r)
          s4[t][r] = __builtin_amdgcn_exp2f(s4[t][r] - mc);

      // in-lane P pack
      uint4 pw0, pw1;
      pw0.x = cvtpk(s4[0][0], s4[0][1]); pw0.y = cvtpk(s4[0][2], s4[0][3]);
      pw0.z = cvtpk(s4[1][0], s4[1][1]); pw0.w = cvtpk(s4[1][2], s4[1][3]);
      pw1.x = cvtpk(s4[2][0], s4[2][1]); pw1.y = cvtpk(s4[2][2], s4[2][3]);
      pw1.z = cvtpk(s4[3][0], s4[3][1]); pw1.w = cvtpk(s4[3][2], s4[3][3]);
      const bf16x8 pa0 = __builtin_bit_cast(bf16x8, pw0);
      const bf16x8 pa1 = __builtin_bit_cast(bf16x8, pw1);

      // PV against k-permuted V + l via ones-column
      __builtin_amdgcn_s_setprio(1);
#pragma unroll
      for (int t2 = 0; t2 < 4; ++t2) {
        bf16x8 vf0 = __builtin_bit_cast(bf16x8, *(const uint4*)&Vt[cur][t2 * 16 + fr][oct * 8]);
        bf16x8 vf1 = __builtin_bit_cast(bf16x8, *(const uint4*)&Vt[cur][t2 * 16 + fr][32 + oct * 8]);
        f32x4 a = acc[tl][t2];
        a = __builtin_amdgcn_mfma_f32_16x16x32_bf16(pa0, vf0, a, 0, 0, 0);
        a = __builtin_amdgcn_mfma_f32_16x16x32_bf16(pa1, vf1, a, 0, 0, 0);
        acc[tl][t2] = a;
      }
      {
        f32x4 a = accl[tl];
        a = __builtin_amdgcn_mfma_f32_16x16x32_bf16(pa0, onesf, a, 0, 0, 0);
        a = __builtin_amdgcn_mfma_f32_16x16x32_bf16(pa1, onesf, a, 0, 0, 0);
        accl[tl] = a;
      }
      __builtin_amdgcn_s_setprio(0);
    }

    if (kb + 1 < nk) {  // write prefetched tile to other buffer
      *(uint4*)&Ks[cur ^ 1][sk][sc] = kr0;
      *(uint4*)&Ks[cur ^ 1][sk][sc + 8] = kr1;
      *(uint4*)&Vt[cur ^ 1][sk][sc] = vr0;
      *(uint4*)&Vt[cur ^ 1][sk][sc + 8] = vr1;
    }
    __syncthreads();
    cur ^= 1;
  }

  // epilogue: normalize by l (already in acc layout), write bf16
#pragma unroll
  for (int tl = 0; tl < 2; ++tl) {
#pragma unroll
    for (int r = 0; r < 4; ++r) {
      float linv = 1.f / accl[tl][r];
      size_t orow = (size_t)(b * 2048 + qtv[tl] * 64 + w * 16 + oct * 4 + r);
#pragma unroll
      for (int t2 = 0; t2 < 4; ++t2)
        attnb[orow * 1024 + h * 64 + t2 * 16 + fr] = f2b(acc[tl][t2][r] * linv);
    }
  }
}

// ---------------------------------------------------------------------------
extern "C" void kernel_launch(void* const* d_in, const int* in_sizes, int n_in,
                              void* d_out, int out_size, void* d_ws, size_t ws_size,
                              hipStream_t stream) {
  const float* x     = (const float*)d_in[0];  // [2,2048,1024]
  const float* w_qkv = (const float*)d_in[1];  // [1024,3072]
  const float* w_out = (const float*)d_in[2];  // [1024,1024]
  const float* freqs = (const float*)d_in[3];  // [2048,64]
  float* out = (float*)d_out;

  char* ws = (char*)d_ws;
  unsigned short* qkvb = (unsigned short*)(ws);             // 25165824
  unsigned short* Qb   = (unsigned short*)(ws + 25165824);  // 8388608
  unsigned short* Kb   = (unsigned short*)(ws + 33554432);  // 8388608
  unsigned short* Vtg  = (unsigned short*)(ws + 41943040);  // 8388608
  unsigned short* attnb= (unsigned short*)(ws + 50331648);  // 8388608
  unsigned short* wqT  = (unsigned short*)(ws + 58720256);  // 6291456
  unsigned short* woT  = (unsigned short*)(ws + 65011712);  // 2097152
  unsigned short* xb   = (unsigned short*)(ws + 67108864);  // 8388608
  // total ws use: 75497472 bytes (72 MiB)

  convert_bf16<<<4096, 256, 0, stream>>>(x, xb, 4096 * 1024);
  transpose_f32_bf16<<<dim3(96, 32), 256, 0, stream>>>(w_qkv, wqT, 1024, 3072);
  transpose_f32_bf16<<<dim3(32, 32), 256, 0, stream>>>(w_out, woT, 1024, 1024);
  gemm_bt<1><<<dim3(24, 32), 256, 0, stream>>>(xb, wqT, qkvb, 4096, 3072, 1024);
  prep_kernel<<<dim3(32, 16, 2), 256, 0, stream>>>(qkvb, freqs, Qb, Kb, Vtg);
  attn_mfma<<<dim3(16, 16, 2), 256, 0, stream>>>(Qb, Kb, Vtg, attnb);
  gemm_bt<0><<<dim3(8, 32), 256, 0, stream>>>(attnb, woT, out, 4096, 1024, 1024);
}